// Round 1
// baseline (579.854 us; speedup 1.0000x reference)
//
#include <hip/hip_runtime.h>

#define L 2048

// ---------------------------------------------------------------------------
// k1: pairs[i] = BASES[argmax_b feat[0, b, i, 0]]   (first-max tie break)
// ---------------------------------------------------------------------------
__global__ void pairs_kernel(const float* __restrict__ feat, float* __restrict__ pairs) {
    int i = blockIdx.x * blockDim.x + threadIdx.x;
    if (i >= L) return;
    float best = feat[(size_t)i * L];   // b = 0, col 0
    int bi = 0;
#pragma unroll
    for (int b = 1; b < 4; ++b) {
        float v = feat[(size_t)b * L * L + (size_t)i * L];
        if (v > best) { best = v; bi = b; }
    }
    const float BV[4] = {2.0f, 3.0f, 5.0f, 7.0f};
    pairs[i] = BV[bi];
}

// ---------------------------------------------------------------------------
// k2: one block per row i.
//   - zero out[i, :]
//   - collect candidates j with |i-j|>=4, base-pair product in {14,15,35},
//     v = 0.5*(con[i][j]+con[j][i]) > 0
//   - bitonic-sort descending by key = (float_bits(v) << 32) | (~edge_flat)
//     (edge_flat = min*L+max  -> exact greedy tie-break order)
//   - store sorted partner indices (u16) + count
// ---------------------------------------------------------------------------
__global__ __launch_bounds__(256) void build_kernel(const float* __restrict__ con,
                                                    const float* __restrict__ pairs,
                                                    unsigned short* __restrict__ lists,
                                                    int* __restrict__ cnt,
                                                    float* __restrict__ out) {
    __shared__ unsigned long long keys[L];
    __shared__ int lcnt;
    const int i = blockIdx.x;
    const int tid = threadIdx.x;
    if (tid == 0) lcnt = 0;
    __syncthreads();
    const float pi = pairs[i];
#pragma unroll
    for (int k = 0; k < L / 256; ++k) {
        int j = tid + k * 256;
        float a = con[(size_t)i * L + j];          // coalesced
        float b = con[(size_t)j * L + i];          // transpose gather (L2/LLC)
        out[(size_t)i * L + j] = 0.0f;             // pre-zero output row
        float v = 0.5f * (a + b);
        int d = i > j ? i - j : j - i;
        float pm = pi * pairs[j];
        bool valid = (d >= 4) && (pm == 14.0f || pm == 15.0f || pm == 35.0f) && (v > 0.0f);
        if (valid) {
            int pos = atomicAdd(&lcnt, 1);
            unsigned int vb = __float_as_uint(v);              // positive: bits order = value order
            unsigned int mn = (unsigned)(i < j ? i : j);
            unsigned int mx = (unsigned)(i < j ? j : i);
            unsigned int ef = mn * (unsigned)L + mx;           // < 2^22
            keys[pos] = ((unsigned long long)vb << 32) |
                        (unsigned long long)(0xFFFFFFFFu - ef); // value desc, then ef asc
        }
    }
    __syncthreads();
    const int c = lcnt;
    // pad to next pow2 >= c with 0-keys (sort to the end in descending order)
    int Np = 1;
    while (Np < c) Np <<= 1;
    if (Np < 2) Np = 2;
    for (int t = c + tid; t < Np; t += 256) keys[t] = 0ull;
    __syncthreads();
    // bitonic sort, descending
    for (int k = 2; k <= Np; k <<= 1) {
        for (int s = k >> 1; s > 0; s >>= 1) {
            for (int x = tid; x < Np; x += 256) {
                int l = x ^ s;
                if (l > x) {
                    unsigned long long a = keys[x], b = keys[l];
                    bool up = ((x & k) == 0);
                    if (up ? (a < b) : (a > b)) { keys[x] = b; keys[l] = a; }
                }
            }
            __syncthreads();
        }
    }
    // emit partner indices in sorted order
    for (int t = tid; t < c; t += 256) {
        unsigned int efinv = (unsigned int)(keys[t] & 0xFFFFFFFFull);
        unsigned int ef = 0xFFFFFFFFu - efinv;
        unsigned int mn = ef >> 11;          // /L
        unsigned int mx = ef & (L - 1);      // %L
        lists[(size_t)i * L + t] = (unsigned short)((mn == (unsigned)i) ? mx : mn);
    }
    if (tid == 0) cnt[i] = c;
}

// ---------------------------------------------------------------------------
// k3: mutual-best (locally dominant) matching == sequential greedy matching.
// Single block, 1024 threads, 2 rows/thread; memo/bestj in LDS; rounds until
// a round produces no match. Matched pairs scatter their value into out.
// ---------------------------------------------------------------------------
__global__ __launch_bounds__(1024) void match_kernel(const float* __restrict__ con,
                                                     const unsigned short* __restrict__ lists,
                                                     const int* __restrict__ cnt,
                                                     float* __restrict__ out) {
    __shared__ short memo[L];
    __shared__ short bestj[L];
    __shared__ int changed;
    const int tid = threadIdx.x;
    const int r0 = tid, r1 = tid + 1024;
    memo[r0] = 0; memo[r1] = 0;
    if (tid == 0) changed = 0;
    int p0 = 0, p1 = 0;
    const int c0 = cnt[r0], c1 = cnt[r1];
    __syncthreads();
    while (true) {
        // ---- phase 1: each free row proposes its best free partner ----
        short b0 = -1, b1 = -1;
        if (!memo[r0]) {
            while (p0 < c0 && memo[lists[(size_t)r0 * L + p0]]) ++p0;
            if (p0 < c0) b0 = (short)lists[(size_t)r0 * L + p0];
        }
        if (!memo[r1]) {
            while (p1 < c1 && memo[lists[(size_t)r1 * L + p1]]) ++p1;
            if (p1 < c1) b1 = (short)lists[(size_t)r1 * L + p1];
        }
        bestj[r0] = b0; bestj[r1] = b1;
        __syncthreads();            // A: proposals visible
        // ---- phase 2: mutual proposals become matches ----
        bool m = false;
        if (b0 >= 0 && r0 < (int)b0 && bestj[b0] == (short)r0) {
            memo[r0] = 1; memo[b0] = 1;
            float v = 0.5f * (con[(size_t)r0 * L + (int)b0] + con[(size_t)(int)b0 * L + r0]);
            out[(size_t)r0 * L + (int)b0] = v;
            out[(size_t)(int)b0 * L + r0] = v;
            m = true;
        }
        if (b1 >= 0 && r1 < (int)b1 && bestj[b1] == (short)r1) {
            memo[r1] = 1; memo[b1] = 1;
            float v = 0.5f * (con[(size_t)r1 * L + (int)b1] + con[(size_t)(int)b1 * L + r1]);
            out[(size_t)r1 * L + (int)b1] = v;
            out[(size_t)(int)b1 * L + r1] = v;
            m = true;
        }
        if (m) changed = 1;
        __syncthreads();            // B: changed + memo visible
        if (changed == 0) break;    // uniform -> no divergent barrier
        __syncthreads();            // C: everyone has read 'changed'
        if (tid == 0) changed = 0;  // reset races with nothing (ordered by A)
    }
}

extern "C" void kernel_launch(void* const* d_in, const int* in_sizes, int n_in,
                              void* d_out, int out_size, void* d_ws, size_t ws_size,
                              hipStream_t stream) {
    const float* con  = (const float*)d_in[0];
    const float* feat = (const float*)d_in[1];
    float* out = (float*)d_out;
    char* ws = (char*)d_ws;
    unsigned short* lists = (unsigned short*)ws;                         // 8 MB
    int*   cnt   = (int*)(ws + (size_t)L * L * sizeof(unsigned short)); // 8 KB
    float* pairs = (float*)(ws + (size_t)L * L * sizeof(unsigned short) + L * sizeof(int));

    pairs_kernel<<<(L + 255) / 256, 256, 0, stream>>>(feat, pairs);
    build_kernel<<<L, 256, 0, stream>>>(con, pairs, lists, cnt, out);
    match_kernel<<<1, 1024, 0, stream>>>(con, lists, cnt, out);
}

// Round 2
// 578.213 us; speedup vs baseline: 1.0028x; 1.0028x over previous
//
#include <hip/hip_runtime.h>

#define L 2048

// ---------------------------------------------------------------------------
// k1: pairs[i] = BASES[argmax_b feat[0, b, i, 0]]   (first-max tie break)
// ---------------------------------------------------------------------------
__global__ void pairs_kernel(const float* __restrict__ feat, float* __restrict__ pairs) {
    int i = blockIdx.x * blockDim.x + threadIdx.x;
    if (i >= L) return;
    float best = feat[(size_t)i * L];   // b = 0, col 0
    int bi = 0;
#pragma unroll
    for (int b = 1; b < 4; ++b) {
        float v = feat[(size_t)b * L * L + (size_t)i * L];
        if (v > best) { best = v; bi = b; }
    }
    const float BV[4] = {2.0f, 3.0f, 5.0f, 7.0f};
    pairs[i] = BV[bi];
}

// ---------------------------------------------------------------------------
// k2: one block per row i (XCD-swizzled so same-XCD blocks take contiguous
// column stripes -> transpose gathers share L2 lines).
//   - zero out[i, :]
//   - collect candidates j with |i-j|>=4, pair product in {14,15,35}, v>0
//   - bitonic-sort descending by (value, ~edge_flat)  == greedy order
//   - store sorted partner indices (u16) + count
// ---------------------------------------------------------------------------
__global__ __launch_bounds__(256) void build_kernel(const float* __restrict__ con,
                                                    const float* __restrict__ pairs,
                                                    unsigned short* __restrict__ lists,
                                                    int* __restrict__ cnt,
                                                    float* __restrict__ out) {
    __shared__ unsigned long long keys[L];
    __shared__ int lcnt;
    const int bid = blockIdx.x;
    const int i = (bid & 7) * 256 + (bid >> 3);   // XCD-bijective swizzle (2048 = 8*256)
    const int tid = threadIdx.x;
    if (tid == 0) lcnt = 0;
    __syncthreads();
    const float pi = pairs[i];
#pragma unroll
    for (int k = 0; k < L / 256; ++k) {
        int j = tid + k * 256;
        float a = con[(size_t)i * L + j];          // coalesced row read
        float b = con[(size_t)j * L + i];          // transpose gather (XCD-local L2)
        out[(size_t)i * L + j] = 0.0f;             // pre-zero output row
        float v = 0.5f * (a + b);
        int d = i > j ? i - j : j - i;
        float pm = pi * pairs[j];
        bool valid = (d >= 4) && (pm == 14.0f || pm == 15.0f || pm == 35.0f) && (v > 0.0f);
        if (valid) {
            int pos = atomicAdd(&lcnt, 1);
            unsigned int vb = __float_as_uint(v);              // positive: bit order == value order
            unsigned int mn = (unsigned)(i < j ? i : j);
            unsigned int mx = (unsigned)(i < j ? j : i);
            unsigned int ef = mn * (unsigned)L + mx;           // < 2^22
            keys[pos] = ((unsigned long long)vb << 32) |
                        (unsigned long long)(0xFFFFFFFFu - ef); // value desc, then ef asc
        }
    }
    __syncthreads();
    const int c = lcnt;
    int Np = 1;
    while (Np < c) Np <<= 1;
    if (Np < 2) Np = 2;
    for (int t = c + tid; t < Np; t += 256) keys[t] = 0ull;
    __syncthreads();
    // bitonic sort, descending
    for (int k = 2; k <= Np; k <<= 1) {
        for (int s = k >> 1; s > 0; s >>= 1) {
            for (int x = tid; x < Np; x += 256) {
                int l = x ^ s;
                if (l > x) {
                    unsigned long long a = keys[x], b = keys[l];
                    bool up = ((x & k) == 0);
                    if (up ? (a < b) : (a > b)) { keys[x] = b; keys[l] = a; }
                }
            }
            __syncthreads();
        }
    }
    for (int t = tid; t < c; t += 256) {
        unsigned int efinv = (unsigned int)(keys[t] & 0xFFFFFFFFull);
        unsigned int ef = 0xFFFFFFFFu - efinv;
        unsigned int mn = ef >> 11;          // /L
        unsigned int mx = ef & (L - 1);      // %L
        lists[(size_t)i * L + t] = (unsigned short)((mn == (unsigned)i) ? mx : mn);
    }
    if (tid == 0) cnt[i] = c;
}

// ---------------------------------------------------------------------------
// k3: mutual-best matching == sequential greedy matching.
// Single block, 1024 threads, 2 rows/thread.
//  - list scan buffered 8 entries / uint4 load (8x fewer dependent loads)
//  - matches recorded to LDS; con gathers + out scatters deferred past loop
//  - 2 barriers/round via parity 'changed' flags
// ---------------------------------------------------------------------------
__global__ __launch_bounds__(1024) void match_kernel(const float* __restrict__ con,
                                                     const unsigned short* __restrict__ lists,
                                                     const int* __restrict__ cnt,
                                                     float* __restrict__ out) {
    __shared__ short memo[L];
    __shared__ short bestj[L];
    __shared__ unsigned int matched[1024];
    __shared__ int nm;
    __shared__ int ch[2];
    const int tid = threadIdx.x;
    const int r0 = tid, r1 = tid + 1024;
    memo[r0] = 0; memo[r1] = 0;
    if (tid == 0) { nm = 0; ch[0] = 0; ch[1] = 0; }
    int p0 = 0, p1 = 0;
    const int c0 = cnt[r0], c1 = cnt[r1];
    const uint4* row0 = reinterpret_cast<const uint4*>(lists + (size_t)r0 * L);
    const uint4* row1 = reinterpret_cast<const uint4*>(lists + (size_t)r1 * L);
    uint4 buf0, buf1;
    int cb0 = -1, cb1 = -1;
    int ph = 0;
    __syncthreads();
    while (true) {
        // ---- phase 1: each free row proposes its best free partner ----
        int b0 = -1, b1 = -1;
        if (!memo[r0]) {
            while (p0 < c0) {
                int nc = p0 >> 3;
                if (nc != cb0) { buf0 = row0[nc]; cb0 = nc; }
                int sl = p0 & 7;
                unsigned w = (sl < 4) ? ((sl < 2) ? buf0.x : buf0.y)
                                      : ((sl < 6) ? buf0.z : buf0.w);
                int cand = (int)((w >> ((sl & 1) * 16)) & 0xFFFFu);
                if (!memo[cand]) { b0 = cand; break; }
                ++p0;
            }
        }
        if (!memo[r1]) {
            while (p1 < c1) {
                int nc = p1 >> 3;
                if (nc != cb1) { buf1 = row1[nc]; cb1 = nc; }
                int sl = p1 & 7;
                unsigned w = (sl < 4) ? ((sl < 2) ? buf1.x : buf1.y)
                                      : ((sl < 6) ? buf1.z : buf1.w);
                int cand = (int)((w >> ((sl & 1) * 16)) & 0xFFFFu);
                if (!memo[cand]) { b1 = cand; break; }
                ++p1;
            }
        }
        bestj[r0] = (short)b0; bestj[r1] = (short)b1;
        __syncthreads();            // A: proposals visible
        // ---- phase 2: mutual proposals become matches (record only) ----
        if (b0 >= 0 && r0 < b0 && bestj[b0] == (short)r0) {
            memo[r0] = 1; memo[b0] = 1;
            matched[atomicAdd(&nm, 1)] = ((unsigned)r0 << 16) | (unsigned)p0;
            ch[ph] = 1;
        }
        if (b1 >= 0 && r1 < b1 && bestj[b1] == (short)r1) {
            memo[r1] = 1; memo[b1] = 1;
            matched[atomicAdd(&nm, 1)] = ((unsigned)r1 << 16) | (unsigned)p1;
            ch[ph] = 1;
        }
        if (tid == 0) ch[ph ^ 1] = 0;   // prep next round's flag (A_{t+1} orders vs readers)
        __syncthreads();            // B: memo/matched/flag visible
        if (ch[ph] == 0) break;     // uniform exit
        ph ^= 1;
    }
    __syncthreads();
    // ---- deferred emission: con gathers + out scatters off the round path ----
    const int m = nm;
    for (int t = tid; t < m; t += 1024) {
        unsigned mp = matched[t];
        int r = (int)(mp >> 16);
        int p = (int)(mp & 0xFFFFu);
        int b = (int)lists[(size_t)r * L + p];
        float v = 0.5f * (con[(size_t)r * L + b] + con[(size_t)b * L + r]);
        out[(size_t)r * L + b] = v;
        out[(size_t)b * L + r] = v;
    }
}

extern "C" void kernel_launch(void* const* d_in, const int* in_sizes, int n_in,
                              void* d_out, int out_size, void* d_ws, size_t ws_size,
                              hipStream_t stream) {
    const float* con  = (const float*)d_in[0];
    const float* feat = (const float*)d_in[1];
    float* out = (float*)d_out;
    char* ws = (char*)d_ws;
    unsigned short* lists = (unsigned short*)ws;                         // 8 MB
    int*   cnt   = (int*)(ws + (size_t)L * L * sizeof(unsigned short)); // 8 KB
    float* pairs = (float*)(ws + (size_t)L * L * sizeof(unsigned short) + L * sizeof(int));

    pairs_kernel<<<(L + 255) / 256, 256, 0, stream>>>(feat, pairs);
    build_kernel<<<L, 256, 0, stream>>>(con, pairs, lists, cnt, out);
    match_kernel<<<1, 1024, 0, stream>>>(con, lists, cnt, out);
}